// Round 3
// baseline (30001.596 us; speedup 1.0000x reference)
//
#include <hip/hip_runtime.h>
#include <hip/hip_bf16.h>
#include <hip/hip_cooperative_groups.h>

namespace cg = cooperative_groups;

// ---------------- sizes ----------------
#define T_STEPS 256
#define MDIM 1024      // MEM_DIM == IN_DIM
#define MROWS 512      // attention memory rows
#define NBLK 256       // persistent grid
#define NTHR 512

// ws float offsets
#define OFF_WG      0u                     // [1024][4096] interleaved (i,o,u,f) per gate
#define OFF_WATT    4194304u               // [1024][1024] transposed W_attnh top
#define OFF_HPRE    5242880u               // [512][1024]
#define OFF_XIOU    5767168u               // [256][3072]
#define OFF_XF      6553600u               // [256][1024]
#define OFF_HCOL    6815744u               // [1024]
#define OFF_H       6816768u               // [1024]
#define OFF_C       6817792u               // [1024]
#define OFF_HNEW    6819072u               // [1024]
#define OFF_ATTV    6820096u               // [1024]
#define OFF_E       6821120u               // [512]

__device__ inline float fast_tanh(float v) {
    float x = fminf(fmaxf(v, -15.f), 15.f);
    float z = __expf(2.f * x);
    return (z - 1.f) / (z + 1.f);
}
__device__ inline float sigm(float v) { return 1.f / (1.f + __expf(-v)); }

__device__ inline float wave_red(float v) {
#pragma unroll
    for (int s = 32; s > 0; s >>= 1) v += __shfl_down(v, s, 64);
    return v;
}

// -------- precompute kernels --------

// Wg[k][4g+{0,1,2,3}] = {W_iouh[k][g], W_iouh[k][m+g], W_iouh[k][2m+g], W_fh[k][g]}
__global__ void build_wg(const float* __restrict__ Wiouh, const float* __restrict__ Wfh,
                         float* __restrict__ Wg) {
    int k = blockIdx.y;
    int g = blockIdx.x * 256 + threadIdx.x;
    float4 v;
    v.x = Wiouh[k * 3072 + g];
    v.y = Wiouh[k * 3072 + 1024 + g];
    v.z = Wiouh[k * 3072 + 2048 + g];
    v.w = Wfh[k * 1024 + g];
    *(float4*)(Wg + (size_t)k * 4096 + 4 * g) = v;
}

// WatT[j][k] = W_attnh[k][j] for k<1024 (top half)
__global__ void transpose_k(const float* __restrict__ src, float* __restrict__ dst) {
    __shared__ float tile[32][33];
    int jx = blockIdx.x * 32 + threadIdx.x;
    int k0 = blockIdx.y * 32;
    for (int i = threadIdx.y; i < 32; i += 8)
        tile[i][threadIdx.x] = src[(size_t)(k0 + i) * 1024 + jx];
    __syncthreads();
    int kx = k0 + threadIdx.x;
    int j0 = blockIdx.x * 32;
    for (int i = threadIdx.y; i < 32; i += 8)
        dst[(size_t)(j0 + i) * 1024 + kx] = tile[threadIdx.x][i];
}

// C[M,N] = A[M,K] @ B[K,N] + b1 + b2 ; M,N multiples of 64, K multiple of 16
__global__ __launch_bounds__(256) void gemm_bias(const float* __restrict__ A,
                                                 const float* __restrict__ B,
                                                 const float* __restrict__ b1,
                                                 const float* __restrict__ b2,
                                                 float* __restrict__ C,
                                                 int M, int N, int K) {
    __shared__ float As[16][68];
    __shared__ float Bs[16][68];
    int t = threadIdx.x;
    int m0 = blockIdx.y * 64, n0 = blockIdx.x * 64;
    int tx = t & 15, ty = t >> 4;
    float acc[4][4] = {};
    for (int kk = 0; kk < K; kk += 16) {
        {
            int m = t >> 2, k4 = (t & 3) * 4;
            const float4 a4 = *(const float4*)(A + (size_t)(m0 + m) * K + kk + k4);
            As[k4 + 0][m] = a4.x; As[k4 + 1][m] = a4.y;
            As[k4 + 2][m] = a4.z; As[k4 + 3][m] = a4.w;
            int kb = t >> 4, n = (t & 15) * 4;
            const float4 b4 = *(const float4*)(B + (size_t)(kk + kb) * N + n0 + n);
            *(float4*)&Bs[kb][n] = b4;
        }
        __syncthreads();
#pragma unroll
        for (int k = 0; k < 16; k++) {
            float a[4], b[4];
            *(float4*)a = *(const float4*)&As[k][ty * 4];
            *(float4*)b = *(const float4*)&Bs[k][tx * 4];
#pragma unroll
            for (int i = 0; i < 4; i++)
#pragma unroll
                for (int j = 0; j < 4; j++)
                    acc[i][j] = fmaf(a[i], b[j], acc[i][j]);
        }
        __syncthreads();
    }
#pragma unroll
    for (int i = 0; i < 4; i++) {
        int m = m0 + ty * 4 + i;
#pragma unroll
        for (int j = 0; j < 4; j++) {
            int n = n0 + tx * 4 + j;
            float v = acc[i][j];
            if (b1) v += b1[n];
            if (b2) v += b2[n];
            C[(size_t)m * N + n] = v;
        }
    }
}

__global__ void colsum_k(const float* __restrict__ H, float* __restrict__ out) {
    int k = blockIdx.x * 256 + threadIdx.x;
    float s = 0.f;
#pragma unroll 8
    for (int r = 0; r < MROWS; r++) s += H[(size_t)r * MDIM + k];
    out[k] = s;
}

// -------- persistent recurrent kernel (cooperative) --------
__global__ __launch_bounds__(NTHR) void recurrent(
    const float* __restrict__ Wg, const float* __restrict__ WatT,
    const float* __restrict__ Hpre, const float* __restrict__ H,
    const float* __restrict__ Hcol, const float* __restrict__ X_iou,
    const float* __restrict__ X_f, const float* __restrict__ Wa,
    float* h, float* c, float* h_new, float* att_v, float* e,
    float* out) {

    cg::grid_group grid = cg::this_grid();

    const int b = blockIdx.x, t = threadIdx.x;
    const int x = b & 7, y = b >> 3;   // XCD-contiguous slices
    __shared__ float smem[1664];

    for (int st = 0; st < T_STEPS; st++) {
        // ---- Phase A: gates + h_new (4 gate columns per block) ----
        {
            float* hs = smem;            // padded h copy, idx k+(k>>5), 1056
            float* red = smem + 1056;    // [32][16]
            float* dotb = smem + 1568;   // [16]
            hs[t + (t >> 5)] = h[t];
            { int k2 = t + 512; hs[k2 + (k2 >> 5)] = h[k2]; }
            __syncthreads();
            const int jt = t & 15, kq = t >> 4;   // jt: column, kq: k-slice of 32
            const int j0 = x * 512 + y * 16;
            const float* wp = Wg + (size_t)(kq * 32) * 4096 + j0 + jt;
            float acc = 0.f;
#pragma unroll 8
            for (int i = 0; i < 32; i++) {
                int k = kq * 32 + i;
                acc = fmaf(hs[k + (k >> 5)], wp[(size_t)i * 4096], acc);
            }
            red[kq * 16 + jt] = acc;
            __syncthreads();
            if (t < 16) {
                float s = 0.f;
#pragma unroll
                for (int q = 0; q < 32; q++) s += red[q * 16 + t];
                dotb[t] = s;
            }
            __syncthreads();
            if (t < 4) {
                int g = x * 128 + y * 4 + t;
                float di = dotb[t * 4 + 0] + X_iou[(size_t)st * 3072 + g];
                float doo = dotb[t * 4 + 1] + X_iou[(size_t)st * 3072 + 1024 + g];
                float du = dotb[t * 4 + 2] + X_iou[(size_t)st * 3072 + 2048 + g];
                float df = dotb[t * 4 + 3] + X_f[(size_t)st * 1024 + g];
                float ig = sigm(di), og = sigm(doo), fg = sigm(df);
                float ug = fast_tanh(du);
                float cn = ig * ug + fg * c[g];
                c[g] = cn;
                h_new[g] = og * fast_tanh(cn);
            }
        }
        grid.sync();

        // ---- Phase B: att_v = h_new @ W_attnh_top (4 rows per block) ----
        {
            const int tr = t >> 7, li = t & 127;
            int j = x * 128 + y * 4 + tr;
            const float* wr = WatT + (size_t)j * 1024;
            float4 w0 = *(const float4*)(wr + li * 4);
            float4 w1 = *(const float4*)(wr + 512 + li * 4);
            float4 h0 = *(const float4*)(h_new + li * 4);
            float4 h1 = *(const float4*)(h_new + 512 + li * 4);
            float acc = w0.x * h0.x + w0.y * h0.y + w0.z * h0.z + w0.w * h0.w
                      + w1.x * h1.x + w1.y * h1.y + w1.z * h1.z + w1.w * h1.w;
            acc = wave_red(acc);
            if ((t & 63) == 0) smem[t >> 6] = acc;
            __syncthreads();
            if (t < 4) att_v[x * 128 + y * 4 + t] = smem[t * 2] + smem[t * 2 + 1];
        }
        grid.sync();

        // ---- Phase C: scores -> e (2 rows per block) ----
        {
            const int rr = t >> 8, li = t & 255;
            int r = x * 64 + y * 2 + rr;
            int k4 = li * 4;
            float4 hp = *(const float4*)(Hpre + (size_t)r * 1024 + k4);
            float4 av = *(const float4*)(att_v + k4);
            float4 wa = *(const float4*)(Wa + k4);
            float acc = fast_tanh(hp.x + av.x) * wa.x + fast_tanh(hp.y + av.y) * wa.y
                      + fast_tanh(hp.z + av.z) * wa.z + fast_tanh(hp.w + av.w) * wa.w;
            acc = wave_red(acc);
            if ((t & 63) == 0) smem[t >> 6] = acc;
            __syncthreads();
            if (t < 2) {
                float sc = smem[t * 4] + smem[t * 4 + 1] + smem[t * 4 + 2] + smem[t * 4 + 3];
                e[x * 64 + y * 2 + t] = __expf(sc);
            }
        }
        grid.sync();

        // ---- Phase D: h_att (blocks 0..63, 16 columns each) ----
        if (b < 64) {
            float* le = smem;          // [512]
            float* sred = smem + 512;  // [8]
            float* pr = smem + 520;    // [32][16]
            float ev = e[t];
            le[t] = ev;
            float sv = wave_red(ev);
            if ((t & 63) == 0) sred[t >> 6] = sv;
            __syncthreads();
            const int kt = t & 15, rq = t >> 4;
            const int k0 = x * 128 + y * 16;
            float pp = 0.f;
#pragma unroll 4
            for (int i2 = 0; i2 < 16; i2++) {
                int r = rq * 16 + i2;
                pp = fmaf(le[r], H[(size_t)r * 1024 + k0 + kt], pp);
            }
            pr[t] = pp;
            __syncthreads();
            if (t < 16) {
                float p = 0.f;
#pragma unroll
                for (int q = 0; q < 32; q++) p += pr[q * 16 + t];
                float S = sred[0] + sred[1] + sred[2] + sred[3]
                        + sred[4] + sred[5] + sred[6] + sred[7];
                int k = k0 + t;
                float hv = Hcol[k] + h_new[k] - p / S;
                h[k] = hv;
                out[(size_t)st * 1024 + k] = hv;
            }
        }
        grid.sync();
    }
}

extern "C" void kernel_launch(void* const* d_in, const int* in_sizes, int n_in,
                              void* d_out, int out_size, void* d_ws, size_t ws_size,
                              hipStream_t stream) {
    const float* inputs  = (const float*)d_in[0];   // [256,1,1024]
    const float* hiddn   = (const float*)d_in[1];   // [512,1024]
    const float* W_ioux  = (const float*)d_in[2];   // [1024,3072]
    const float* b_ioux  = (const float*)d_in[3];
    const float* W_iouh  = (const float*)d_in[4];   // [1024,3072]
    const float* b_iouh  = (const float*)d_in[5];
    const float* W_fx    = (const float*)d_in[6];   // [1024,1024]
    const float* b_fx    = (const float*)d_in[7];
    const float* W_fh    = (const float*)d_in[8];   // [1024,1024]
    const float* b_fh    = (const float*)d_in[9];
    const float* Wa      = (const float*)d_in[10];  // [1,1024]
    const float* W_attnh = (const float*)d_in[11];  // [2048,1024]
    const float* b_attnh = (const float*)d_in[12];

    float* ws = (float*)d_ws;
    float* Wg    = ws + OFF_WG;
    float* WatT  = ws + OFF_WATT;
    float* Hpre  = ws + OFF_HPRE;
    float* X_iou = ws + OFF_XIOU;
    float* X_f   = ws + OFF_XF;
    float* Hcol  = ws + OFF_HCOL;
    float* h     = ws + OFF_H;
    float* c     = ws + OFF_C;
    float* h_new = ws + OFF_HNEW;
    float* att_v = ws + OFF_ATTV;
    float* e     = ws + OFF_E;
    float* out   = (float*)d_out;   // reference output dtype is float32

    // zero h, c (ws is poisoned before every timed launch)
    hipMemsetAsync(ws + OFF_H, 0, 2048 * sizeof(float), stream);

    build_wg<<<dim3(4, 1024), 256, 0, stream>>>(W_iouh, W_fh, Wg);
    transpose_k<<<dim3(32, 32), dim3(32, 8), 0, stream>>>(W_attnh, WatT);
    gemm_bias<<<dim3(48, 4), 256, 0, stream>>>(inputs, W_ioux, b_ioux, b_iouh, X_iou, 256, 3072, 1024);
    gemm_bias<<<dim3(16, 4), 256, 0, stream>>>(inputs, W_fx, b_fx, b_fh, X_f, 256, 1024, 1024);
    gemm_bias<<<dim3(16, 8), 256, 0, stream>>>(hiddn, W_attnh + 1024 * 1024, b_attnh, nullptr, Hpre, 512, 1024, 1024);
    colsum_k<<<4, 256, 0, stream>>>(hiddn, Hcol);

    const float* Hm = hiddn;
    void* kargs[] = {
        (void*)&Wg, (void*)&WatT, (void*)&Hpre, (void*)&Hm, (void*)&Hcol,
        (void*)&X_iou, (void*)&X_f, (void*)&Wa, (void*)&h, (void*)&c,
        (void*)&h_new, (void*)&att_v, (void*)&e, (void*)&out
    };
    hipLaunchCooperativeKernel((const void*)recurrent, dim3(NBLK), dim3(NTHR),
                               kargs, 0, stream);
}

// Round 4
// 5771.610 us; speedup vs baseline: 5.1981x; 5.1981x over previous
//
#include <hip/hip_runtime.h>
#include <hip/hip_bf16.h>

// ---------------- sizes ----------------
#define T_STEPS 256
#define MDIM 1024      // MEM_DIM == IN_DIM
#define MROWS 512      // attention memory rows
#define NBLK 256       // persistent grid
#define NTHR 512

// ws float offsets
#define OFF_WG      0u                     // [1024][4096] interleaved (i,o,u,f) per gate
#define OFF_WATT    4194304u               // [1024][1024] transposed W_attnh top
#define OFF_HPRE    5242880u               // [512][1024]
#define OFF_XIOU    5767168u               // [256][3072]
#define OFF_XF      6553600u               // [256][1024]
#define OFF_HCOL    6815744u               // [1024]
#define OFF_H       6816768u               // [1024]
#define OFF_C       (OFF_H + 1024u)        // [1024]
#define OFF_BAR     (OFF_H + 2048u)        // 1024 u32 barrier cells
#define OFF_HNEW    (OFF_H + 3072u)        // [1024]
#define OFF_ATTV    (OFF_H + 4096u)        // [1024]
#define OFF_E       (OFF_H + 5120u)        // [512]

__device__ inline float fast_tanh(float v) {
    float x = fminf(fmaxf(v, -15.f), 15.f);
    float z = __expf(2.f * x);
    return (z - 1.f) / (z + 1.f);
}
__device__ inline float sigm(float v) { return 1.f / (1.f + __expf(-v)); }

__device__ inline float wave_red(float v) {
#pragma unroll
    for (int s = 32; s > 0; s >>= 1) v += __shfl_down(v, s, 64);
    return v;
}

// device-scope relaxed atomics: bypass L2 (serialize at LLC), emit NO buffer_inv
__device__ inline float gload(const float* p) {
    return __hip_atomic_load(p, __ATOMIC_RELAXED, __HIP_MEMORY_SCOPE_AGENT);
}
__device__ inline void gstore(float* p, float v) {
    __hip_atomic_store(p, v, __ATOMIC_RELAXED, __HIP_MEMORY_SCOPE_AGENT);
}

// two-level tree barrier, monotonic epochs, NO acquire fence (keeps L2 intact).
// Correctness: __syncthreads drains vmcnt (data stores LLC-acked) before arrival;
// flag visibility implies all arrivals done; post-barrier data reads are
// LLC-direct relaxed atomics, so no invalidate needed.
__device__ inline void gsync(unsigned* bar, unsigned ep, int cell) {
    __syncthreads();
    if (threadIdx.x == 0) {
        unsigned o = __hip_atomic_fetch_add(&bar[cell * 32], 1u, __ATOMIC_RELEASE,
                                            __HIP_MEMORY_SCOPE_AGENT);
        if (o == ep * 16u + 15u) {
            unsigned r = __hip_atomic_fetch_add(&bar[512], 1u, __ATOMIC_RELAXED,
                                                __HIP_MEMORY_SCOPE_AGENT);
            if (r == ep * 16u + 15u)
                __hip_atomic_store(&bar[544], ep + 1u, __ATOMIC_RELAXED,
                                   __HIP_MEMORY_SCOPE_AGENT);
        }
        while (__hip_atomic_load(&bar[544], __ATOMIC_RELAXED,
                                 __HIP_MEMORY_SCOPE_AGENT) < ep + 1u)
            __builtin_amdgcn_s_sleep(2);
    }
    __asm__ volatile("" ::: "memory");
    __syncthreads();
}

// -------- precompute kernels --------

// Wg[k][4g+{0,1,2,3}] = {W_iouh[k][g], W_iouh[k][m+g], W_iouh[k][2m+g], W_fh[k][g]}
__global__ void build_wg(const float* __restrict__ Wiouh, const float* __restrict__ Wfh,
                         float* __restrict__ Wg) {
    int k = blockIdx.y;
    int g = blockIdx.x * 256 + threadIdx.x;
    float4 v;
    v.x = Wiouh[k * 3072 + g];
    v.y = Wiouh[k * 3072 + 1024 + g];
    v.z = Wiouh[k * 3072 + 2048 + g];
    v.w = Wfh[k * 1024 + g];
    *(float4*)(Wg + (size_t)k * 4096 + 4 * g) = v;
}

// WatT[j][k] = W_attnh[k][j] for k<1024 (top half)
__global__ void transpose_k(const float* __restrict__ src, float* __restrict__ dst) {
    __shared__ float tile[32][33];
    int jx = blockIdx.x * 32 + threadIdx.x;
    int k0 = blockIdx.y * 32;
    for (int i = threadIdx.y; i < 32; i += 8)
        tile[i][threadIdx.x] = src[(size_t)(k0 + i) * 1024 + jx];
    __syncthreads();
    int kx = k0 + threadIdx.x;
    int j0 = blockIdx.x * 32;
    for (int i = threadIdx.y; i < 32; i += 8)
        dst[(size_t)(j0 + i) * 1024 + kx] = tile[threadIdx.x][i];
}

// C[M,N] = A[M,K] @ B[K,N] + b1 + b2 ; M,N multiples of 64, K multiple of 16
__global__ __launch_bounds__(256) void gemm_bias(const float* __restrict__ A,
                                                 const float* __restrict__ B,
                                                 const float* __restrict__ b1,
                                                 const float* __restrict__ b2,
                                                 float* __restrict__ C,
                                                 int M, int N, int K) {
    __shared__ float As[16][68];
    __shared__ float Bs[16][68];
    int t = threadIdx.x;
    int m0 = blockIdx.y * 64, n0 = blockIdx.x * 64;
    int tx = t & 15, ty = t >> 4;
    float acc[4][4] = {};
    for (int kk = 0; kk < K; kk += 16) {
        {
            int m = t >> 2, k4 = (t & 3) * 4;
            const float4 a4 = *(const float4*)(A + (size_t)(m0 + m) * K + kk + k4);
            As[k4 + 0][m] = a4.x; As[k4 + 1][m] = a4.y;
            As[k4 + 2][m] = a4.z; As[k4 + 3][m] = a4.w;
            int kb = t >> 4, n = (t & 15) * 4;
            const float4 b4 = *(const float4*)(B + (size_t)(kk + kb) * N + n0 + n);
            *(float4*)&Bs[kb][n] = b4;
        }
        __syncthreads();
#pragma unroll
        for (int k = 0; k < 16; k++) {
            float a[4], b[4];
            *(float4*)a = *(const float4*)&As[k][ty * 4];
            *(float4*)b = *(const float4*)&Bs[k][tx * 4];
#pragma unroll
            for (int i = 0; i < 4; i++)
#pragma unroll
                for (int j = 0; j < 4; j++)
                    acc[i][j] = fmaf(a[i], b[j], acc[i][j]);
        }
        __syncthreads();
    }
#pragma unroll
    for (int i = 0; i < 4; i++) {
        int m = m0 + ty * 4 + i;
#pragma unroll
        for (int j = 0; j < 4; j++) {
            int n = n0 + tx * 4 + j;
            float v = acc[i][j];
            if (b1) v += b1[n];
            if (b2) v += b2[n];
            C[(size_t)m * N + n] = v;
        }
    }
}

__global__ void colsum_k(const float* __restrict__ H, float* __restrict__ out) {
    int k = blockIdx.x * 256 + threadIdx.x;
    float s = 0.f;
#pragma unroll 8
    for (int r = 0; r < MROWS; r++) s += H[(size_t)r * MDIM + k];
    out[k] = s;
}

// -------- persistent recurrent kernel --------
__global__ __launch_bounds__(NTHR) void recurrent(
    const float* __restrict__ Wg, const float* __restrict__ WatT,
    const float* __restrict__ Hpre, const float* __restrict__ H,
    const float* __restrict__ Hcol, const float* __restrict__ X_iou,
    const float* __restrict__ X_f, const float* __restrict__ Wa,
    float* h, float* c, float* h_new, float* att_v, float* e,
    unsigned* bar, float* out) {

    const int b = blockIdx.x, t = threadIdx.x;
    const int x = b & 7, y = b >> 3;   // XCD-contiguous slices
    const int cell = b & 15;
    unsigned ep = 0;
    __shared__ float smem[1664];

    for (int st = 0; st < T_STEPS; st++) {
        // ---- Phase A: gates + h_new (4 gate columns per block) ----
        {
            float* hs = smem;            // padded h copy, idx k+(k>>5), 1056
            float* red = smem + 1056;    // [32][16]
            float* dotb = smem + 1568;   // [16]
            float h0 = gload(h + t), h1 = gload(h + t + 512);
            hs[t + (t >> 5)] = h0;
            { int k2 = t + 512; hs[k2 + (k2 >> 5)] = h1; }
            __syncthreads();
            const int jt = t & 15, kq = t >> 4;   // jt: column, kq: k-slice of 32
            const int j0 = x * 512 + y * 16;
            const float* wp = Wg + (size_t)(kq * 32) * 4096 + j0 + jt;
            float acc = 0.f;
#pragma unroll 8
            for (int i = 0; i < 32; i++) {
                int k = kq * 32 + i;
                acc = fmaf(hs[k + (k >> 5)], wp[(size_t)i * 4096], acc);
            }
            red[kq * 16 + jt] = acc;
            __syncthreads();
            if (t < 16) {
                float s = 0.f;
#pragma unroll
                for (int q = 0; q < 32; q++) s += red[q * 16 + t];
                dotb[t] = s;
            }
            __syncthreads();
            if (t < 4) {
                int g = x * 128 + y * 4 + t;
                float di = dotb[t * 4 + 0] + X_iou[(size_t)st * 3072 + g];
                float doo = dotb[t * 4 + 1] + X_iou[(size_t)st * 3072 + 1024 + g];
                float du = dotb[t * 4 + 2] + X_iou[(size_t)st * 3072 + 2048 + g];
                float df = dotb[t * 4 + 3] + X_f[(size_t)st * 1024 + g];
                float ig = sigm(di), og = sigm(doo), fg = sigm(df);
                float ug = fast_tanh(du);
                float cn = ig * ug + fg * c[g];
                c[g] = cn;
                gstore(h_new + g, og * fast_tanh(cn));
            }
        }
        gsync(bar, ep++, cell);

        // ---- Phase B: att_v = h_new @ W_attnh_top (4 rows per block) ----
        {
            float* hn = smem;            // [1024] staged h_new
            hn[t] = gload(h_new + t);
            hn[t + 512] = gload(h_new + t + 512);
            __syncthreads();
            const int tr = t >> 7, li = t & 127;
            int j = x * 128 + y * 4 + tr;
            const float* wr = WatT + (size_t)j * 1024;
            float4 w0 = *(const float4*)(wr + li * 4);
            float4 w1 = *(const float4*)(wr + 512 + li * 4);
            float4 a0 = *(const float4*)&hn[li * 4];
            float4 a1 = *(const float4*)&hn[512 + li * 4];
            float acc = w0.x * a0.x + w0.y * a0.y + w0.z * a0.z + w0.w * a0.w
                      + w1.x * a1.x + w1.y * a1.y + w1.z * a1.z + w1.w * a1.w;
            acc = wave_red(acc);
            __syncthreads();     // smem reuse guard (hn -> reduction slots)
            if ((t & 63) == 0) smem[1024 + (t >> 6)] = acc;
            __syncthreads();
            if (t < 4) gstore(att_v + x * 128 + y * 4 + t,
                              smem[1024 + t * 2] + smem[1024 + t * 2 + 1]);
        }
        gsync(bar, ep++, cell);

        // ---- Phase C: scores -> e (2 rows per block) ----
        {
            float* av = smem;            // [1024] staged att_v
            av[t] = gload(att_v + t);
            av[t + 512] = gload(att_v + t + 512);
            __syncthreads();
            const int rr = t >> 8, li = t & 255;
            int r = x * 64 + y * 2 + rr;
            int k4 = li * 4;
            float4 hp = *(const float4*)(Hpre + (size_t)r * 1024 + k4);
            float4 a4 = *(const float4*)&av[k4];
            float4 wa = *(const float4*)(Wa + k4);
            float acc = fast_tanh(hp.x + a4.x) * wa.x + fast_tanh(hp.y + a4.y) * wa.y
                      + fast_tanh(hp.z + a4.z) * wa.z + fast_tanh(hp.w + a4.w) * wa.w;
            acc = wave_red(acc);
            __syncthreads();
            if ((t & 63) == 0) smem[1024 + (t >> 6)] = acc;
            __syncthreads();
            if (t < 2) {
                float sc = smem[1024 + t * 4] + smem[1024 + t * 4 + 1]
                         + smem[1024 + t * 4 + 2] + smem[1024 + t * 4 + 3];
                gstore(e + x * 64 + y * 2 + t, __expf(sc));
            }
        }
        gsync(bar, ep++, cell);

        // ---- Phase D: h_att (blocks 0..63, 16 columns each) ----
        if (b < 64) {
            float* le = smem;          // [512]
            float* sred = smem + 512;  // [8]
            float* pr = smem + 520;    // [32][16]
            float ev = gload(e + t);
            le[t] = ev;
            float sv = wave_red(ev);
            if ((t & 63) == 0) sred[t >> 6] = sv;
            __syncthreads();
            const int kt = t & 15, rq = t >> 4;
            const int k0 = x * 128 + y * 16;
            float pp = 0.f;
#pragma unroll 4
            for (int i2 = 0; i2 < 16; i2++) {
                int r = rq * 16 + i2;
                pp = fmaf(le[r], H[(size_t)r * 1024 + k0 + kt], pp);
            }
            pr[t] = pp;
            __syncthreads();
            if (t < 16) {
                float p = 0.f;
#pragma unroll
                for (int q = 0; q < 32; q++) p += pr[q * 16 + t];
                float S = sred[0] + sred[1] + sred[2] + sred[3]
                        + sred[4] + sred[5] + sred[6] + sred[7];
                int k = k0 + t;
                float hv = Hcol[k] + gload(h_new + k) - p / S;
                gstore(h + k, hv);
                out[(size_t)st * 1024 + k] = hv;
            }
        }
        gsync(bar, ep++, cell);
    }
}

extern "C" void kernel_launch(void* const* d_in, const int* in_sizes, int n_in,
                              void* d_out, int out_size, void* d_ws, size_t ws_size,
                              hipStream_t stream) {
    const float* inputs  = (const float*)d_in[0];   // [256,1,1024]
    const float* hiddn   = (const float*)d_in[1];   // [512,1024]
    const float* W_ioux  = (const float*)d_in[2];   // [1024,3072]
    const float* b_ioux  = (const float*)d_in[3];
    const float* W_iouh  = (const float*)d_in[4];   // [1024,3072]
    const float* b_iouh  = (const float*)d_in[5];
    const float* W_fx    = (const float*)d_in[6];   // [1024,1024]
    const float* b_fx    = (const float*)d_in[7];
    const float* W_fh    = (const float*)d_in[8];   // [1024,1024]
    const float* b_fh    = (const float*)d_in[9];
    const float* Wa      = (const float*)d_in[10];  // [1,1024]
    const float* W_attnh = (const float*)d_in[11];  // [2048,1024]
    const float* b_attnh = (const float*)d_in[12];

    float* ws = (float*)d_ws;
    float* Wg    = ws + OFF_WG;
    float* WatT  = ws + OFF_WATT;
    float* Hpre  = ws + OFF_HPRE;
    float* X_iou = ws + OFF_XIOU;
    float* X_f   = ws + OFF_XF;
    float* Hcol  = ws + OFF_HCOL;
    float* h     = ws + OFF_H;
    float* c     = ws + OFF_C;
    unsigned* bar = (unsigned*)(ws + OFF_BAR);
    float* h_new = ws + OFF_HNEW;
    float* att_v = ws + OFF_ATTV;
    float* e     = ws + OFF_E;
    float* out   = (float*)d_out;   // reference output dtype is float32

    // zero h, c, barrier cells (ws is poisoned before every timed launch)
    hipMemsetAsync(ws + OFF_H, 0, 3072 * sizeof(float), stream);

    build_wg<<<dim3(4, 1024), 256, 0, stream>>>(W_iouh, W_fh, Wg);
    transpose_k<<<dim3(32, 32), dim3(32, 8), 0, stream>>>(W_attnh, WatT);
    gemm_bias<<<dim3(48, 4), 256, 0, stream>>>(inputs, W_ioux, b_ioux, b_iouh, X_iou, 256, 3072, 1024);
    gemm_bias<<<dim3(16, 4), 256, 0, stream>>>(inputs, W_fx, b_fx, b_fh, X_f, 256, 1024, 1024);
    gemm_bias<<<dim3(16, 8), 256, 0, stream>>>(hiddn, W_attnh + 1024 * 1024, b_attnh, nullptr, Hpre, 512, 1024, 1024);
    colsum_k<<<4, 256, 0, stream>>>(hiddn, Hcol);

    recurrent<<<NBLK, NTHR, 0, stream>>>(Wg, WatT, Hpre, hiddn, Hcol, X_iou, X_f, Wa,
                                         h, c, h_new, att_v, e, bar, out);
}